// Round 2
// 224.510 us; speedup vs baseline: 1.0101x; 1.0101x over previous
//
#include <hip/hip_runtime.h>

// Problem constants (B=16, T=512, N=2048, U=64) — all inputs/outputs FP32.
#define N_DIM 2048
#define U_DIM 64
#define M_DIM 8192   // B*T
#define K_DIM 2048   // = N

typedef __bf16 bf16x8 __attribute__((ext_vector_type(8)));
typedef float  floatx4 __attribute__((ext_vector_type(4)));
typedef unsigned short ushort8 __attribute__((ext_vector_type(8)));

#define AS1 __attribute__((address_space(1)))
#define AS3 __attribute__((address_space(3)))

__device__ __forceinline__ unsigned short f_to_bf16_rne(float f) {
    unsigned int x;
    __builtin_memcpy(&x, &f, 4);
    x += 0x7fffu + ((x >> 16) & 1u);
    return (unsigned short)(x >> 16);
}

// ---------------------------------------------------------------------------
// Kernel 1: wbar[k] = mean_i W[i,k]  (fp32), bmean = mean(b)
// ---------------------------------------------------------------------------
__global__ __launch_bounds__(256) void prep_kernel(
    const float* __restrict__ W, const float* __restrict__ b,
    float* __restrict__ wbar, float* __restrict__ bmean) {
    int k = blockIdx.x * 256 + threadIdx.x;
    float s = 0.f;
#pragma unroll
    for (int i = 0; i < U_DIM; ++i) s += W[i * N_DIM + k];
    wbar[k] = s * (1.f / U_DIM);

    if (blockIdx.x == 0 && threadIdx.x < 64) {
        float v = b[threadIdx.x];
#pragma unroll
        for (int off = 32; off > 0; off >>= 1) v += __shfl_down(v, off);
        if (threadIdx.x == 0) bmean[0] = v * (1.f / U_DIM);
    }
}

// ---------------------------------------------------------------------------
// Kernel 2 (merged): blocks [0, 2048): weff[j,k] = bf16(Adj[j,k]*wbar[k])
//                    blocks [2048, 10240): xbf = bf16(x)
// ---------------------------------------------------------------------------
__global__ __launch_bounds__(256) void weff_convx_kernel(
    const float* __restrict__ Adj, const float* __restrict__ wbar,
    unsigned short* __restrict__ weff,
    const float* __restrict__ x, unsigned short* __restrict__ xbf) {
    if (blockIdx.x < 2048) {
        long long idx = ((long long)blockIdx.x * 256 + threadIdx.x) * 8;
        int k = (int)(idx & (N_DIM - 1));
        floatx4 a0 = *(const floatx4*)(Adj + idx);
        floatx4 a1 = *(const floatx4*)(Adj + idx + 4);
        floatx4 w0 = *(const floatx4*)(wbar + k);
        floatx4 w1 = *(const floatx4*)(wbar + k + 4);
        ushort8 ov;
#pragma unroll
        for (int j = 0; j < 4; ++j) {
            ov[j]     = f_to_bf16_rne(a0[j] * w0[j]);
            ov[j + 4] = f_to_bf16_rne(a1[j] * w1[j]);
        }
        *(ushort8*)(weff + idx) = ov;
    } else {
        long long idx = ((long long)(blockIdx.x - 2048) * 256 + threadIdx.x) * 8;
        floatx4 a0 = *(const floatx4*)(x + idx);
        floatx4 a1 = *(const floatx4*)(x + idx + 4);
        ushort8 ov;
#pragma unroll
        for (int j = 0; j < 4; ++j) {
            ov[j]     = f_to_bf16_rne(a0[j]);
            ov[j + 4] = f_to_bf16_rne(a1[j]);
        }
        *(ushort8*)(xbf + idx) = ov;
    }
}

// Fallback converter for chunked path (small ws)
__global__ __launch_bounds__(256) void convx_kernel(
    const float* __restrict__ x, unsigned short* __restrict__ xbf) {
    long long idx = ((long long)blockIdx.x * 256 + threadIdx.x) * 8;
    floatx4 a0 = *(const floatx4*)(x + idx);
    floatx4 a1 = *(const floatx4*)(x + idx + 4);
    ushort8 ov;
#pragma unroll
    for (int j = 0; j < 4; ++j) {
        ov[j]     = f_to_bf16_rne(a0[j]);
        ov[j + 4] = f_to_bf16_rne(a1[j]);
    }
    *(ushort8*)(xbf + idx) = ov;
}

// ---------------------------------------------------------------------------
// Kernel 3: C[m,j] = sum_k A[m,k]*Bt[j,k] + bmean   (bf16 in, fp32 acc/out)
//
// 256x256 tile, BK=64 (32 K-tiles), 8 waves (2M x 4N), 512 threads.
// Per wave: 128x64 output = 8x4 frags of mfma_f32_16x16x32_bf16.
// LDS: double-buffered sA[2][256][64] + sB[2][256][64] = 128 KB, rows 128 B,
// XOR swizzle slot = kc ^ (row&7) (0 bank conflicts measured in round 0).
//
// Counted-vmcnt 2-deep pipeline (T3/T4/T5), STAGE placed AFTER the reads'
// barrier to keep only 12 operand frags live at a time (~210 VGPRs, no spill):
//   per K-tile t (p = t&1):
//     s_waitcnt vmcnt(8)  [vmcnt(0) on last tile] ; s_barrier  - tile t in LDS
//     for s in {0,1}: ds_read 12 frags ; lgkmcnt(0)+sched_barrier ;
//                     setprio(1) 32 MFMA setprio(0)
//     s_barrier                                   - all waves done reading buf[p]
//     STAGE(buf[p], tile t+2)                     - 8 global_load_lds, in flight
// Steady state: 16 loads outstanding, wait to 8, never drained to 0.
//
// XCD mapping: grid = mtiles*8, nt = id&7 (one n-tile per XCD -> 1 MB B-panel
// L2-resident per XCD), mt = id>>3.
// ---------------------------------------------------------------------------
#define BM 256
#define BN 256
#define BK 64
#define NT (K_DIM / BK)   // 32

__global__ __launch_bounds__(512, 2) void gemm_bt_kernel(
    const unsigned short* __restrict__ A,    // [M, K] bf16 bits (xbf)
    const unsigned short* __restrict__ Bt,   // [N, K] bf16 bits (weff)
    const float* __restrict__ bmeanp,
    float* __restrict__ C,                   // [M, N] fp32
    int mtiles) {
    __shared__ __align__(16) unsigned short sA[2][BM * BK];  // 2 x 32 KB
    __shared__ __align__(16) unsigned short sB[2][BN * BK];  // 2 x 32 KB

    const int id   = blockIdx.x;
    const int nt   = id & 7;        // n-tile == XCD (round-robin dispatch)
    const int mt   = id >> 3;
    const int tile_m = mt * BM;
    const int tile_n = nt * BN;

    const int tid  = threadIdx.x;
    const int w    = tid >> 6;      // wave 0..7
    const int lane = tid & 63;
    const int wm   = w >> 2;        // 0..1  (M split)
    const int wn   = w & 3;         // 0..3  (N split)

    const float bmean = bmeanp[0];

    // --- staging: wave w stages A-chunks and B-chunks [w*4, w*4+4).
    // chunk = 8 rows x 128 B = 1 KB (one wave-instruction of global_load_lds).
    // lane l -> row_in_chunk = l>>3, LDS slot = l&7; pre-swizzled global col
    // kc = (l&7) ^ (l>>3) so LDS[row][slot] = global[row][slot ^ (row&7)].
    const int srow = lane >> 3;              // 0..7
    const int skc  = (lane & 7) ^ srow;      // swizzled fetch chunk
    const unsigned short* gA0 = A  + (size_t)(tile_m + w * 32 + srow) * K_DIM + skc * 8;
    const unsigned short* gB0 = Bt + (size_t)(tile_n + w * 32 + srow) * K_DIM + skc * 8;

    // --- fragment read offsets (elements). 16x16x32 frag: m(n)=lane&15,
    // k = (lane>>4)*8 + j within the K=32 step; k-step s adds 32.
    const int fr = lane & 15;
    const int fq = lane >> 4;       // 0..3
    int aoff[2], boff[2];
#pragma unroll
    for (int s = 0; s < 2; ++s) {
        int slot = ((s * 4 + fq) ^ (fr & 7)) * 8;
        aoff[s] = (wm * 128 + fr) * BK + slot;
        boff[s] = (wn * 64 + fr) * BK + slot;
    }

    floatx4 acc[8][4];
#pragma unroll
    for (int mi = 0; mi < 8; ++mi)
#pragma unroll
        for (int ni = 0; ni < 4; ++ni) acc[mi][ni] = (floatx4){0.f, 0.f, 0.f, 0.f};

    // stage one K-tile (8 wave-instructions: 4 A-chunks + 4 B-chunks)
    #define STAGE(p, kt)                                                          \
        do {                                                                      \
            const int koff_ = (kt) * BK;                                          \
            _Pragma("unroll")                                                     \
            for (int i_ = 0; i_ < 4; ++i_) {                                      \
                __builtin_amdgcn_global_load_lds(                                 \
                    (const AS1 void*)(gA0 + koff_ + (size_t)i_ * 8 * K_DIM),      \
                    (AS3 void*)(&sA[(p)][(w * 4 + i_) * 8 * BK]), 16, 0, 0);      \
                __builtin_amdgcn_global_load_lds(                                 \
                    (const AS1 void*)(gB0 + koff_ + (size_t)i_ * 8 * K_DIM),      \
                    (AS3 void*)(&sB[(p)][(w * 4 + i_) * 8 * BK]), 16, 0, 0);      \
            }                                                                     \
        } while (0)

    // prologue: tiles 0 and 1 in flight (16 outstanding per wave)
    STAGE(0, 0);
    STAGE(1, 1);

    for (int t = 0; t < NT; ++t) {
        const int p = t & 1;

        // tile t's 8 loads (mine) landed; keep the newer 8 in flight.
        if (t == NT - 1) asm volatile("s_waitcnt vmcnt(0)" ::: "memory");
        else             asm volatile("s_waitcnt vmcnt(8)" ::: "memory");
        // all waves: tile t fully in LDS
        __builtin_amdgcn_s_barrier();

#pragma unroll
        for (int s = 0; s < 2; ++s) {
            bf16x8 af[8], bfr[4];
#pragma unroll
            for (int mi = 0; mi < 8; ++mi)
                af[mi] = *(const bf16x8*)&sA[p][aoff[s] + mi * 16 * BK];
#pragma unroll
            for (int ni = 0; ni < 4; ++ni)
                bfr[ni] = *(const bf16x8*)&sB[p][boff[s] + ni * 16 * BK];
            asm volatile("s_waitcnt lgkmcnt(0)" ::: "memory");
            __builtin_amdgcn_sched_barrier(0);     // rule #18: pin MFMAs after wait
            __builtin_amdgcn_s_setprio(1);
#pragma unroll
            for (int mi = 0; mi < 8; ++mi)
#pragma unroll
                for (int ni = 0; ni < 4; ++ni)
                    acc[mi][ni] = __builtin_amdgcn_mfma_f32_16x16x32_bf16(
                        af[mi], bfr[ni], acc[mi][ni], 0, 0, 0);
            __builtin_amdgcn_s_setprio(0);
        }

        // all waves done reading buf[p] -> it is writable
        __builtin_amdgcn_s_barrier();

        // 2-deep prefetch into the buffer just freed; stays in flight across
        // the next iteration's vmcnt(8).
        if (t + 2 < NT) STAGE(p, t + 2);
    }
    #undef STAGE

    // Epilogue. 16x16 C/D: col = lane&15, row = (lane>>4)*4 + reg  [m89/m91]
    const int crow = tile_m + wm * 128 + fq * 4;
    const int ccol = tile_n + wn * 64 + fr;
#pragma unroll
    for (int mi = 0; mi < 8; ++mi)
#pragma unroll
        for (int ni = 0; ni < 4; ++ni)
#pragma unroll
            for (int r = 0; r < 4; ++r) {
                int gm = crow + mi * 16 + r;
                int gn = ccol + ni * 16;
                C[(size_t)gm * N_DIM + gn] = acc[mi][ni][r] + bmean;
            }
    (void)mtiles;
}

// ---------------------------------------------------------------------------
extern "C" void kernel_launch(void* const* d_in, const int* in_sizes, int n_in,
                              void* d_out, int out_size, void* d_ws, size_t ws_size,
                              hipStream_t stream) {
    (void)in_sizes; (void)n_in; (void)out_size;
    const float* x   = (const float*)d_in[0];  // [16,512,2048]
    const float* Adj = (const float*)d_in[1];  // [2048,2048]
    const float* W   = (const float*)d_in[2];  // [64,2048]
    const float* b   = (const float*)d_in[3];  // [64]
    float* out = (float*)d_out;                // [16,512,2048] fp32

    // ws: wbar @0 (8 KB) | bmean @8192 | weff bf16 @16384 (8.39 MB) | xbf
    char* ws = (char*)d_ws;
    float* wbar  = (float*)ws;
    float* bmean = (float*)(ws + 8192);
    unsigned short* weff = (unsigned short*)(ws + 16384);
    const size_t weff_bytes = (size_t)N_DIM * N_DIM * 2;
    const size_t xbf_off = 16384 + weff_bytes;
    unsigned short* xbf = (unsigned short*)(ws + xbf_off);

    size_t avail = (ws_size > xbf_off) ? (ws_size - xbf_off) : 0;
    long long max_rows = (long long)(avail / ((size_t)K_DIM * 2)) / BM * BM;
    if (max_rows < BM) max_rows = BM;
    if (max_rows > M_DIM) max_rows = M_DIM;

    prep_kernel<<<N_DIM / 256, 256, 0, stream>>>(W, b, wbar, bmean);

    if (max_rows == M_DIM) {
        // full-size path: merged weff+convx, then one 256^2 8-wave GEMM
        weff_convx_kernel<<<2048 + M_DIM, 256, 0, stream>>>(Adj, wbar, weff, x, xbf);
        gemm_bt_kernel<<<(M_DIM / BM) * (N_DIM / BN), 512, 0, stream>>>(
            xbf, weff, bmean, out, M_DIM / BM);
    } else {
        weff_convx_kernel<<<2048, 256, 0, stream>>>(Adj, wbar, weff, x, xbf);
        for (long long m0 = 0; m0 < M_DIM; m0 += max_rows) {
            long long rows = (M_DIM - m0 < max_rows) ? (M_DIM - m0) : max_rows;
            convx_kernel<<<(int)rows, 256, 0, stream>>>(x + m0 * K_DIM, xbf);
            gemm_bt_kernel<<<(int)(rows / BM) * (N_DIM / BN), 512, 0, stream>>>(
                xbf, weff, bmean, out + m0 * (size_t)N_DIM, (int)(rows / BM));
        }
    }
}

// Round 3
// 217.406 us; speedup vs baseline: 1.0431x; 1.0327x over previous
//
#include <hip/hip_runtime.h>

// Problem constants (B=16, T=512, N=2048, U=64) — all inputs/outputs FP32.
#define N_DIM 2048
#define U_DIM 64
#define M_DIM 8192   // B*T
#define K_DIM 2048   // = N

typedef __bf16 bf16x8 __attribute__((ext_vector_type(8)));
typedef float  floatx4 __attribute__((ext_vector_type(4)));
typedef unsigned short ushort8 __attribute__((ext_vector_type(8)));

#define AS1 __attribute__((address_space(1)))
#define AS3 __attribute__((address_space(3)))

__device__ __forceinline__ unsigned short f_to_bf16_rne(float f) {
    unsigned int x;
    __builtin_memcpy(&x, &f, 4);
    x += 0x7fffu + ((x >> 16) & 1u);
    return (unsigned short)(x >> 16);
}

// ---------------------------------------------------------------------------
// Kernel 1: wbar[k] = mean_i W[i,k]  (fp32), bmean = mean(b)
// ---------------------------------------------------------------------------
__global__ __launch_bounds__(256) void prep_kernel(
    const float* __restrict__ W, const float* __restrict__ b,
    float* __restrict__ wbar, float* __restrict__ bmean) {
    int k = blockIdx.x * 256 + threadIdx.x;
    float s = 0.f;
#pragma unroll
    for (int i = 0; i < U_DIM; ++i) s += W[i * N_DIM + k];
    wbar[k] = s * (1.f / U_DIM);

    if (blockIdx.x == 0 && threadIdx.x < 64) {
        float v = b[threadIdx.x];
#pragma unroll
        for (int off = 32; off > 0; off >>= 1) v += __shfl_down(v, off);
        if (threadIdx.x == 0) bmean[0] = v * (1.f / U_DIM);
    }
}

// ---------------------------------------------------------------------------
// Kernel 2 (merged): blocks [0, 2048): weff[j,k] = bf16(Adj[j,k]*wbar[k])
//                    blocks [2048, 10240): xbf = bf16(x)
// ---------------------------------------------------------------------------
__global__ __launch_bounds__(256) void weff_convx_kernel(
    const float* __restrict__ Adj, const float* __restrict__ wbar,
    unsigned short* __restrict__ weff,
    const float* __restrict__ x, unsigned short* __restrict__ xbf) {
    if (blockIdx.x < 2048) {
        long long idx = ((long long)blockIdx.x * 256 + threadIdx.x) * 8;
        int k = (int)(idx & (N_DIM - 1));
        floatx4 a0 = *(const floatx4*)(Adj + idx);
        floatx4 a1 = *(const floatx4*)(Adj + idx + 4);
        floatx4 w0 = *(const floatx4*)(wbar + k);
        floatx4 w1 = *(const floatx4*)(wbar + k + 4);
        ushort8 ov;
#pragma unroll
        for (int j = 0; j < 4; ++j) {
            ov[j]     = f_to_bf16_rne(a0[j] * w0[j]);
            ov[j + 4] = f_to_bf16_rne(a1[j] * w1[j]);
        }
        *(ushort8*)(weff + idx) = ov;
    } else {
        long long idx = ((long long)(blockIdx.x - 2048) * 256 + threadIdx.x) * 8;
        floatx4 a0 = *(const floatx4*)(x + idx);
        floatx4 a1 = *(const floatx4*)(x + idx + 4);
        ushort8 ov;
#pragma unroll
        for (int j = 0; j < 4; ++j) {
            ov[j]     = f_to_bf16_rne(a0[j]);
            ov[j + 4] = f_to_bf16_rne(a1[j]);
        }
        *(ushort8*)(xbf + idx) = ov;
    }
}

// Fallback converter for chunked path (small ws)
__global__ __launch_bounds__(256) void convx_kernel(
    const float* __restrict__ x, unsigned short* __restrict__ xbf) {
    long long idx = ((long long)blockIdx.x * 256 + threadIdx.x) * 8;
    floatx4 a0 = *(const floatx4*)(x + idx);
    floatx4 a1 = *(const floatx4*)(x + idx + 4);
    ushort8 ov;
#pragma unroll
    for (int j = 0; j < 4; ++j) {
        ov[j]     = f_to_bf16_rne(a0[j]);
        ov[j + 4] = f_to_bf16_rne(a1[j]);
    }
    *(ushort8*)(xbf + idx) = ov;
}

// ---------------------------------------------------------------------------
// Kernel 3: C[m,j] = sum_k A[m,k]*Bt[j,k] + bmean   (bf16 in, fp32 acc/out)
//
// 256x256 tile, BK=64 (32 K-tiles), 8 waves (2M x 4N), 512 threads.
// Per wave: 128x64 output = 8x4 frags of mfma_f32_16x16x32_bf16.
// LDS: double-buffered sA/sB = 128 KB; XOR swizzle slot = kc ^ (row&7)
// (0 bank conflicts measured).
//
// R3b: 4-cluster pipelined K-tile. Rotating fragment regs keep <=64 operand
// VGPRs live (R2 evidence: acc lives in AGPRs; VGPR cap 256 - 128 AGPR).
// Per K-tile t (p=t&1):
//   vmcnt(8) [0 on last] ; B1            - tile t in LDS
//   init reads: bf_s0[4] + af_a[4]       - only exposed LDS burst (~500 cyc)
//   c1: issue af_b[4]+bf_s1[4] ; 16 MFMA (mi0-3,s0)   - reads hide under MFMA
//   c2: issue af_c[4]          ; 16 MFMA (mi4-7,s0)
//   c3: issue af_d[4]          ; 16 MFMA (mi0-3,s1)
//   c4: lgkm(0) ; B2 (buf p free) ; STAGE(t+2 -> p) ; 16 MFMA (mi4-7,s1)
// Steady state: 16 gloads outstanding, vmcnt to 8, never drained mid-loop.
//
// XCD mapping: grid = mtiles*8, nt = id&7 (one n-tile per XCD -> 1 MB B-panel
// L2-resident per XCD), mt = id>>3.
// ---------------------------------------------------------------------------
#define BM 256
#define BN 256
#define BK 64
#define NT (K_DIM / BK)   // 32

__global__ __launch_bounds__(512, 2) void gemm_bt_kernel(
    const unsigned short* __restrict__ A,    // [M, K] bf16 bits (xbf)
    const unsigned short* __restrict__ Bt,   // [N, K] bf16 bits (weff)
    const float* __restrict__ bmeanp,
    float* __restrict__ C,                   // [M, N] fp32
    int mtiles) {
    __shared__ __align__(16) unsigned short sA[2][BM * BK];  // 2 x 32 KB
    __shared__ __align__(16) unsigned short sB[2][BN * BK];  // 2 x 32 KB

    const int id   = blockIdx.x;
    const int nt   = id & 7;        // n-tile == XCD (round-robin dispatch)
    const int mt   = id >> 3;
    const int tile_m = mt * BM;
    const int tile_n = nt * BN;

    const int tid  = threadIdx.x;
    const int w    = tid >> 6;      // wave 0..7
    const int lane = tid & 63;
    const int wm   = w >> 2;        // 0..1  (M split)
    const int wn   = w & 3;         // 0..3  (N split)

    const float bmean = bmeanp[0];

    // --- staging: wave w stages A-chunks and B-chunks [w*4, w*4+4).
    // chunk = 8 rows x 128 B = 1 KB. lane l -> row l>>3, LDS slot l&7;
    // pre-swizzled global col kc = (l&7)^(l>>3): LDS[row][slot]=G[row][slot^row].
    const int srow = lane >> 3;              // 0..7
    const int skc  = (lane & 7) ^ srow;      // swizzled fetch chunk
    const unsigned short* gA0 = A  + (size_t)(tile_m + w * 32 + srow) * K_DIM + skc * 8;
    const unsigned short* gB0 = Bt + (size_t)(tile_n + w * 32 + srow) * K_DIM + skc * 8;

    // --- fragment read offsets. 16x16x32 frag: m(n)=lane&15, k=(lane>>4)*8+j;
    // k-step s adds 32.
    const int fr = lane & 15;
    const int fq = lane >> 4;       // 0..3
    int aoff[2], boff[2];
#pragma unroll
    for (int s = 0; s < 2; ++s) {
        int slot = ((s * 4 + fq) ^ (fr & 7)) * 8;
        aoff[s] = (wm * 128 + fr) * BK + slot;
        boff[s] = (wn * 64 + fr) * BK + slot;
    }

    floatx4 acc[8][4];
#pragma unroll
    for (int mi = 0; mi < 8; ++mi)
#pragma unroll
        for (int ni = 0; ni < 4; ++ni) acc[mi][ni] = (floatx4){0.f, 0.f, 0.f, 0.f};

    #define STAGE(p, kt)                                                          \
        do {                                                                      \
            const int koff_ = (kt) * BK;                                          \
            _Pragma("unroll")                                                     \
            for (int i_ = 0; i_ < 4; ++i_) {                                      \
                __builtin_amdgcn_global_load_lds(                                 \
                    (const AS1 void*)(gA0 + koff_ + (size_t)i_ * 8 * K_DIM),      \
                    (AS3 void*)(&sA[(p)][(w * 4 + i_) * 8 * BK]), 16, 0, 0);      \
                __builtin_amdgcn_global_load_lds(                                 \
                    (const AS1 void*)(gB0 + koff_ + (size_t)i_ * 8 * K_DIM),      \
                    (AS3 void*)(&sB[(p)][(w * 4 + i_) * 8 * BK]), 16, 0, 0);      \
            }                                                                     \
        } while (0)

    // prologue: tiles 0 and 1 in flight (16 outstanding per wave)
    STAGE(0, 0);
    STAGE(1, 1);

    for (int t = 0; t < NT; ++t) {
        const int p = t & 1;

        // tile t's 8 loads (oldest 8 of <=16) landed; newer 8 stay in flight.
        if (t == NT - 1) asm volatile("s_waitcnt vmcnt(0)" ::: "memory");
        else             asm volatile("s_waitcnt vmcnt(8)" ::: "memory");
        __builtin_amdgcn_s_barrier();               // B1: tile t visible

        bf16x8 bf0[4], bf1[4], afa[4], afb[4], afc[4], afd[4];

        // init burst: 8 reads (the only exposed LDS latency per tile)
#pragma unroll
        for (int ni = 0; ni < 4; ++ni)
            bf0[ni] = *(const bf16x8*)&sB[p][boff[0] + ni * 16 * BK];
#pragma unroll
        for (int i = 0; i < 4; ++i)
            afa[i] = *(const bf16x8*)&sA[p][aoff[0] + i * 16 * BK];
        __builtin_amdgcn_sched_barrier(0);

        // ---- cluster 1: prefetch af_b + bf_s1; MFMA mi0-3, s0
#pragma unroll
        for (int i = 0; i < 4; ++i)
            afb[i] = *(const bf16x8*)&sA[p][aoff[0] + (4 + i) * 16 * BK];
#pragma unroll
        for (int ni = 0; ni < 4; ++ni)
            bf1[ni] = *(const bf16x8*)&sB[p][boff[1] + ni * 16 * BK];
        __builtin_amdgcn_sched_barrier(0);
        __builtin_amdgcn_s_setprio(1);
#pragma unroll
        for (int mi = 0; mi < 4; ++mi)
#pragma unroll
            for (int ni = 0; ni < 4; ++ni)
                acc[mi][ni] = __builtin_amdgcn_mfma_f32_16x16x32_bf16(
                    afa[mi], bf0[ni], acc[mi][ni], 0, 0, 0);
        __builtin_amdgcn_s_setprio(0);

        // ---- cluster 2: prefetch af_c; MFMA mi4-7, s0
#pragma unroll
        for (int i = 0; i < 4; ++i)
            afc[i] = *(const bf16x8*)&sA[p][aoff[1] + i * 16 * BK];
        __builtin_amdgcn_sched_barrier(0);
        __builtin_amdgcn_s_setprio(1);
#pragma unroll
        for (int mi = 4; mi < 8; ++mi)
#pragma unroll
            for (int ni = 0; ni < 4; ++ni)
                acc[mi][ni] = __builtin_amdgcn_mfma_f32_16x16x32_bf16(
                    afb[mi - 4], bf0[ni], acc[mi][ni], 0, 0, 0);
        __builtin_amdgcn_s_setprio(0);

        // ---- cluster 3: prefetch af_d; MFMA mi0-3, s1
#pragma unroll
        for (int i = 0; i < 4; ++i)
            afd[i] = *(const bf16x8*)&sA[p][aoff[1] + (4 + i) * 16 * BK];
        __builtin_amdgcn_sched_barrier(0);
        __builtin_amdgcn_s_setprio(1);
#pragma unroll
        for (int mi = 0; mi < 4; ++mi)
#pragma unroll
            for (int ni = 0; ni < 4; ++ni)
                acc[mi][ni] = __builtin_amdgcn_mfma_f32_16x16x32_bf16(
                    afc[mi], bf1[ni], acc[mi][ni], 0, 0, 0);
        __builtin_amdgcn_s_setprio(0);

        // ---- cluster 4: drain my reads, free buf p, stage t+2, MFMA mi4-7 s1
        asm volatile("s_waitcnt lgkmcnt(0)" ::: "memory");
        __builtin_amdgcn_sched_barrier(0);
        __builtin_amdgcn_s_barrier();               // B2: buf p free
        if (t + 2 < NT) STAGE(p, t + 2);
        __builtin_amdgcn_sched_barrier(0);
        __builtin_amdgcn_s_setprio(1);
#pragma unroll
        for (int mi = 4; mi < 8; ++mi)
#pragma unroll
            for (int ni = 0; ni < 4; ++ni)
                acc[mi][ni] = __builtin_amdgcn_mfma_f32_16x16x32_bf16(
                    afd[mi - 4], bf1[ni], acc[mi][ni], 0, 0, 0);
        __builtin_amdgcn_s_setprio(0);
    }
    #undef STAGE

    // Epilogue. 16x16 C/D: col = lane&15, row = (lane>>4)*4 + reg  [m89/m91]
    const int crow = tile_m + wm * 128 + fq * 4;
    const int ccol = tile_n + wn * 64 + fr;
#pragma unroll
    for (int mi = 0; mi < 8; ++mi)
#pragma unroll
        for (int ni = 0; ni < 4; ++ni)
#pragma unroll
            for (int r = 0; r < 4; ++r) {
                int gm = crow + mi * 16 + r;
                int gn = ccol + ni * 16;
                C[(size_t)gm * N_DIM + gn] = acc[mi][ni][r] + bmean;
            }
    (void)mtiles;
}

// ---------------------------------------------------------------------------
extern "C" void kernel_launch(void* const* d_in, const int* in_sizes, int n_in,
                              void* d_out, int out_size, void* d_ws, size_t ws_size,
                              hipStream_t stream) {
    (void)in_sizes; (void)n_in; (void)out_size;
    const float* x   = (const float*)d_in[0];  // [16,512,2048]
    const float* Adj = (const float*)d_in[1];  // [2048,2048]
    const float* W   = (const float*)d_in[2];  // [64,2048]
    const float* b   = (const float*)d_in[3];  // [64]
    float* out = (float*)d_out;                // [16,512,2048] fp32

    // ws: wbar @0 (8 KB) | bmean @8192 | weff bf16 @16384 (8.39 MB) | xbf
    char* ws = (char*)d_ws;
    float* wbar  = (float*)ws;
    float* bmean = (float*)(ws + 8192);
    unsigned short* weff = (unsigned short*)(ws + 16384);
    const size_t weff_bytes = (size_t)N_DIM * N_DIM * 2;
    const size_t xbf_off = 16384 + weff_bytes;
    unsigned short* xbf = (unsigned short*)(ws + xbf_off);

    size_t avail = (ws_size > xbf_off) ? (ws_size - xbf_off) : 0;
    long long max_rows = (long long)(avail / ((size_t)K_DIM * 2)) / BM * BM;
    if (max_rows < BM) max_rows = BM;
    if (max_rows > M_DIM) max_rows = M_DIM;

    prep_kernel<<<N_DIM / 256, 256, 0, stream>>>(W, b, wbar, bmean);

    if (max_rows == M_DIM) {
        // full-size path: merged weff+convx, then one 256^2 8-wave GEMM
        weff_convx_kernel<<<2048 + M_DIM, 256, 0, stream>>>(Adj, wbar, weff, x, xbf);
        gemm_bt_kernel<<<(M_DIM / BM) * (N_DIM / BN), 512, 0, stream>>>(
            xbf, weff, bmean, out, M_DIM / BM);
    } else {
        weff_convx_kernel<<<2048, 256, 0, stream>>>(Adj, wbar, weff, x, xbf);
        for (long long m0 = 0; m0 < M_DIM; m0 += max_rows) {
            long long rows = (M_DIM - m0 < max_rows) ? (M_DIM - m0) : max_rows;
            convx_kernel<<<(int)rows, 256, 0, stream>>>(x + m0 * K_DIM, xbf);
            gemm_bt_kernel<<<(int)(rows / BM) * (N_DIM / BN), 512, 0, stream>>>(
                xbf, weff, bmean, out + m0 * (size_t)N_DIM, (int)(rows / BM));
        }
    }
}